// Round 14
// baseline (287.589 us; speedup 1.0000x reference)
//
#include <hip/hip_runtime.h>
#include <stdint.h>

// ---------- types ----------
typedef __attribute__((ext_vector_type(8))) __bf16 bf16x8;
typedef __attribute__((ext_vector_type(4))) float   f32x4;

__device__ __forceinline__ float bf2f(unsigned short u) {
    union { unsigned int i; float f; } v; v.i = ((unsigned int)u) << 16; return v.f;
}
__device__ __forceinline__ unsigned short f2bf(float f) {  // round-to-nearest-even
    unsigned int x = __builtin_bit_cast(unsigned int, f);
    x += 0x7FFFu + ((x >> 16) & 1u);
    return (unsigned short)(x >> 16);
}

// ---------- fused fp32 -> bf16 cast: x (12582912 f4) + Wth/Wph (65536 f4 each) + Wg (262144 f4) ----------
__global__ __launch_bounds__(256) void cast_all(const float* __restrict__ x,
                                                const float* __restrict__ wth,
                                                const float* __restrict__ wph,
                                                const float* __restrict__ wg,
                                                unsigned short* __restrict__ xb,
                                                unsigned short* __restrict__ wcat,
                                                unsigned short* __restrict__ wgb) {
    constexpr int NX  = 12582912;            // x float4 count
    constexpr int NW  = 65536;               // per 256x1024 weight
    constexpr int TOT = NX + 2 * NW + 262144;
    int i = blockIdx.x * blockDim.x + threadIdx.x;
    const int stride = gridDim.x * blockDim.x;
    for (; i < TOT; i += stride) {
        const float4* s4; ushort4* d4; int off;
        if (i < NX)                { s4 = (const float4*)x;   d4 = (ushort4*)xb;              off = i; }
        else if (i < NX + NW)      { s4 = (const float4*)wth; d4 = (ushort4*)wcat;            off = i - NX; }
        else if (i < NX + 2 * NW)  { s4 = (const float4*)wph; d4 = (ushort4*)(wcat + 262144); off = i - NX - NW; }
        else                       { s4 = (const float4*)wg;  d4 = (ushort4*)wgb;             off = i - NX - 2 * NW; }
        float4 v = s4[off];
        ushort4 o;
        o.x = f2bf(v.x); o.y = f2bf(v.y); o.z = f2bf(v.z); o.w = f2bf(v.w);
        d4[off] = o;
    }
}

// ---------- GEMM (m97 structure): 128x128 tile, 4 waves, single 32KB LDS buffer ----------
// C[M,NTOT] = A[M,K] * W[NTOT,K]^T, bf16 in, fp32 accum. 256 threads = 2x2 waves,
// each wave a 64x64 output. Simple per-K-tile loop: stage -> sync -> MFMA -> sync;
// stall cover comes from 4 resident blocks/CU (TLP), not intra-block pipelining.
// Chunk-XOR swizzle (0 conflicts), XCD-aware mapping (nt fastest).
// MODE 0: += bias (split col 256), bf16 out via LDS-coalesced epilogue (36KB LDS).
// MODE 1: relu, fp32 direct stores (32KB LDS).
template<int NTOT, int MODE, int NTI>
__global__ __launch_bounds__(256, 4)
void gemm97(const unsigned short* __restrict__ A,
            const unsigned short* __restrict__ W,
            const float* __restrict__ bias0,
            const float* __restrict__ bias1,
            unsigned short* __restrict__ outb,
            float* __restrict__ outf) {
    constexpr int K  = 1024;
    constexpr int NT = 16;                         // K-tiles of 64
    constexpr int LDS_SHORTS = (MODE == 0) ? 18432 : 16384;
    __shared__ unsigned short lds[LDS_SHORTS];     // A[128][64] | B[128][64] (+epilogue room)

    const int t    = threadIdx.x;
    const int wave = t >> 6;
    const int lane = t & 63;

    const int bid = blockIdx.x;
    const int xcd = bid & 7;                       // HW round-robins blocks over 8 XCDs
    const int j   = bid >> 3;
    const int mt  = xcd * 48 + j / NTI;            // 384 M-tiles, 48 per XCD
    const int nt  = j % NTI;                       // nt fastest: A-tile reused NTI times

    const int wr = wave >> 1;                      // 0..1 : rows wr*64..
    const int wc = wave & 1;                       // 0..1 : cols wc*64..

    const size_t aBase = (size_t)mt * 128 * K;
    const size_t bBase = (size_t)nt * 128 * K;

    // staging: 256 thr x 16B = 4KB = 32 rows of 128B per instr; pre-swizzled source
    const int srow = t >> 3;                       // 0..31
    const int scol = ((t & 7) ^ (srow & 7)) << 3;  // element offset
    const unsigned short* gA = A + aBase + (size_t)srow * K + scol;
    const unsigned short* gB = W + bBase + (size_t)srow * K + scol;

    auto STAGE = [&](int tile) {                   // 4 instr A + 4 instr B
#pragma unroll
        for (int i = 0; i < 4; ++i)
            __builtin_amdgcn_global_load_lds(
                (const __attribute__((address_space(1))) void*)(gA + (size_t)(i * 32) * K + tile * 64),
                (__attribute__((address_space(3))) void*)(lds + i * 2048 + wave * 512), 16, 0, 0);
#pragma unroll
        for (int i = 0; i < 4; ++i)
            __builtin_amdgcn_global_load_lds(
                (const __attribute__((address_space(1))) void*)(gB + (size_t)(i * 32) * K + tile * 64),
                (__attribute__((address_space(3))) void*)(lds + 8192 + i * 2048 + wave * 512), 16, 0, 0);
    };

    const int lr  = lane & 15;
    const int lkc = lane >> 4;
    auto LDA = [&](int mi, int kk) -> bf16x8 {
        const int row = wr * 64 + mi * 16 + lr;
        const int ch  = (kk * 4 + lkc) ^ (row & 7);
        return *reinterpret_cast<const bf16x8*>(&lds[row * 64 + ch * 8]);
    };
    auto LDB = [&](int ni, int kk) -> bf16x8 {
        const int row = wc * 64 + ni * 16 + lr;
        const int ch  = (kk * 4 + lkc) ^ (row & 7);
        return *reinterpret_cast<const bf16x8*>(&lds[8192 + row * 64 + ch * 8]);
    };

    f32x4 acc[4][4];
#pragma unroll
    for (int m = 0; m < 4; ++m)
#pragma unroll
        for (int n = 0; n < 4; ++n) acc[m][n] = f32x4{0.f, 0.f, 0.f, 0.f};

    for (int tt = 0; tt < NT; ++tt) {
        STAGE(tt);
        __syncthreads();                           // drains vmcnt(0): tile landed
        bf16x8 af[4][2], bfr[4][2];
#pragma unroll
        for (int m = 0; m < 4; ++m) { af[m][0] = LDA(m, 0); af[m][1] = LDA(m, 1); }
#pragma unroll
        for (int n = 0; n < 4; ++n) { bfr[n][0] = LDB(n, 0); bfr[n][1] = LDB(n, 1); }
#pragma unroll
        for (int m = 0; m < 4; ++m)
#pragma unroll
            for (int n = 0; n < 4; ++n)
#pragma unroll
                for (int kk = 0; kk < 2; ++kk)
                    acc[m][n] = __builtin_amdgcn_mfma_f32_16x16x32_bf16(af[m][kk], bfr[n][kk], acc[m][n], 0, 0, 0);
        __syncthreads();                           // reads done before next stage overwrites
    }

    // -------- epilogue --------
    const int rowOff = (lane >> 4) * 4;            // C/D: col = lane&15, row = rowOff + r
    if (MODE == 1) {
#pragma unroll
        for (int m = 0; m < 4; ++m)
#pragma unroll
            for (int n = 0; n < 4; ++n)
#pragma unroll
                for (int r = 0; r < 4; ++r)
                    outf[(size_t)(mt * 128 + wr * 64 + m * 16 + rowOff + r) * NTOT
                         + nt * 128 + wc * 64 + n * 16 + lr] = fmaxf(acc[m][n][r], 0.f);
    } else {
        unsigned short* lu = lds;                  // 4 regions x 64 x 72 shorts = 18432
#pragma unroll
        for (int mq = 0; mq < 4; ++mq)
#pragma unroll
            for (int n = 0; n < 4; ++n) {
                const int gc = nt * 128 + wc * 64 + n * 16 + lr;
                const float bv = (gc < 256) ? bias0[gc] : bias1[gc - 256];
#pragma unroll
                for (int r = 0; r < 4; ++r)
                    lu[wave * 4608 + (mq * 16 + rowOff + r) * 72 + n * 16 + lr] =
                        f2bf(acc[mq][n][r] + bv);
            }
        __syncthreads();
#pragma unroll
        for (int it = 0; it < 8; ++it) {           // 128 rows x 128 cols bf16
            const int flat = it * 2048 + t * 8;    // shorts
            const int row  = flat >> 7;            // 0..127
            const int col  = flat & 127;
            const int wv   = (row >> 6) * 2 + (col >> 6);
            uint4 v = *reinterpret_cast<const uint4*>(&lu[wv * 4608 + (row & 63) * 72 + (col & 63)]);
            *reinterpret_cast<uint4*>(outb + (size_t)(mt * 128 + row) * NTOT + nt * 128 + col) = v;
        }
    }
}

// ---------- per-batch: sim -> mask -> softmax -> relation + agg (in-place over x_bf16) ----------
// Vectorized LDS access: float4 dot reads, ushort4 agg reads + packed stores.
__global__ __launch_bounds__(256)
void relation_kernel(const unsigned short* __restrict__ TP,   // [M,512] bf16: theta|phi
                     const float* __restrict__ boxes,         // [M,4]
                     unsigned short* __restrict__ xagg,       // [M,1024] bf16 in, agg out (aliased)
                     float* __restrict__ relout) {            // [BT,12,12] fp32
    __shared__ float th[12][260];   // +4 pad
    __shared__ float ph[12][260];
    __shared__ unsigned short xls[12 * 1024];
    __shared__ float cx[12], cy[12];
    __shared__ float sim[12][12];
    __shared__ float rel[12][12];

    const int b = blockIdx.x;
    const int t = threadIdx.x;

    if (t < 12) {
        const float* bx = boxes + ((size_t)b * 12 + t) * 4;
        cx[t] = (bx[0] + bx[2]) * 0.5f;
        cy[t] = (bx[1] + bx[3]) * 0.5f;
    }
    const uint4* tp4 = (const uint4*)(TP + (size_t)b * 6144);
    for (int c = t; c < 768; c += 256) {
        uint4 v = tp4[c];
        const unsigned short* pv = (const unsigned short*)&v;
        const int n = c >> 6;
        const int c0 = (c & 63) << 3;
        if (c0 < 256) {
#pragma unroll
            for (int jj = 0; jj < 8; ++jj) th[n][c0 + jj] = bf2f(pv[jj]);
        } else {
#pragma unroll
            for (int jj = 0; jj < 8; ++jj) ph[n][c0 - 256 + jj] = bf2f(pv[jj]);
        }
    }
    const uint4* x4 = (const uint4*)(xagg + (size_t)b * 12288);
    uint4* xl4 = (uint4*)xls;
    for (int c = t; c < 1536; c += 256) xl4[c] = x4[c];
    __syncthreads();

    if (t < 144) {
        const int n = t / 12, m = t - (t / 12) * 12;
        const float4* tn = (const float4*)&th[n][0];
        const float4* pm = (const float4*)&ph[m][0];
        float a = 0.f;
#pragma unroll 8
        for (int r = 0; r < 64; ++r) {   // same accumulation order as scalar loop
            float4 av = tn[r], bv4 = pm[r];
            a += av.x * bv4.x; a += av.y * bv4.y; a += av.z * bv4.z; a += av.w * bv4.w;
        }
        const float dx = cx[n] - cx[m], dy = cy[n] - cy[m];
        const float d2 = dx * dx + dy * dy;
        const float thr = 31.4f;  // POS_THRESHOLD * OW
        sim[n][m] = (d2 > thr * thr) ? -__builtin_inff() : a * 0.0625f;
    }
    __syncthreads();

    if (t < 12) {
        float mx = -__builtin_inff();
#pragma unroll
        for (int m = 0; m < 12; ++m) mx = fmaxf(mx, sim[t][m]);
        float e[12]; float s = 0.f;
#pragma unroll
        for (int m = 0; m < 12; ++m) { e[m] = expf(sim[t][m] - mx); s += e[m]; }
        const float inv = 1.f / s;
#pragma unroll
        for (int m = 0; m < 12; ++m) {
            const float r = e[m] * inv;
            rel[t][m] = r;
            relout[(size_t)b * 144 + t * 12 + m] = r;
        }
    }
    __syncthreads();

    unsigned short* aggp = xagg + (size_t)b * 12288;
    {
        const int f0 = t * 4;
        float xv[12][4];
#pragma unroll
        for (int m = 0; m < 12; ++m) {
            ushort4 u = *reinterpret_cast<const ushort4*>(&xls[m * 1024 + f0]);
            xv[m][0] = bf2f(u.x); xv[m][1] = bf2f(u.y);
            xv[m][2] = bf2f(u.z); xv[m][3] = bf2f(u.w);
        }
        float rl[12];
#pragma unroll
        for (int n = 0; n < 12; ++n) {
#pragma unroll
            for (int m = 0; m < 12; ++m) rl[m] = rel[n][m];
            ushort4 o;
            float a0 = 0.f, a1 = 0.f, a2 = 0.f, a3 = 0.f;
#pragma unroll
            for (int m = 0; m < 12; ++m) {
                a0 += rl[m] * xv[m][0];
                a1 += rl[m] * xv[m][1];
                a2 += rl[m] * xv[m][2];
                a3 += rl[m] * xv[m][3];
            }
            o.x = f2bf(a0); o.y = f2bf(a1); o.z = f2bf(a2); o.w = f2bf(a3);
            *reinterpret_cast<ushort4*>(&aggp[n * 1024 + f0]) = o;
        }
    }
}

// ---------- launcher ----------
extern "C" void kernel_launch(void* const* d_in, const int* in_sizes, int n_in,
                              void* d_out, int out_size, void* d_ws, size_t ws_size,
                              hipStream_t stream) {
    const float* x     = (const float*)d_in[0];  // [4096,12,1024] fp32
    const float* boxes = (const float*)d_in[1];  // [49152,4]
    const float* Wth   = (const float*)d_in[2];  // [256,1024]
    const float* bth   = (const float*)d_in[3];  // [256]
    const float* Wph   = (const float*)d_in[4];  // [256,1024]
    const float* bph   = (const float*)d_in[5];  // [256]
    const float* Wg    = (const float*)d_in[6];  // [1024,1024]
    float* out = (float*)d_out;                  // 49152*1024 out | 4096*144 relation

    const int M = 49152;
    const size_t XE = (size_t)M * 1024;

    char* ws = (char*)d_ws;
    unsigned short* xb   = (unsigned short*)ws;                 // bf16 x, later agg (in place)
    unsigned short* TP   = (unsigned short*)(ws + 100663296);   // [M,512] bf16 theta|phi
    unsigned short* Wcat = (unsigned short*)(ws + 150994944);   // [512,1024] bf16
    unsigned short* Wgb  = (unsigned short*)(ws + 152043520);   // [1024,1024] bf16

    cast_all<<<2048, 256, 0, stream>>>(x, Wth, Wph, Wg, xb, Wcat, Wgb);

    // gemm0: 384 M-tiles (48/XCD) x NTI=4 -> 1536 blocks, 4 resident/CU
    gemm97<512, 0, 4><<<dim3(1536), 256, 0, stream>>>(xb, Wcat, bth, bph, TP, nullptr);

    relation_kernel<<<4096, 256, 0, stream>>>(TP, boxes, xb, out + XE);

    // gemm1: 384 M-tiles (48/XCD) x NTI=8 -> 3072 blocks, 4 resident/CU
    gemm97<1024, 1, 8><<<dim3(3072), 256, 0, stream>>>(xb, Wgb, nullptr, nullptr, nullptr, out);
}